// Round 3
// baseline (259.638 us; speedup 1.0000x reference)
//
#include <hip/hip_runtime.h>
#include <hip/hip_bf16.h>

#define DIM  512
#define FEAT 64
#define BATCH 2048

#define ROWS_PER_BLOCK 512
#define TILES_PER_WAVE 8   // ROWS_PER_BLOCK / (4 waves * 16 rows)

using bf16x8 = __attribute__((ext_vector_type(8))) short;
using f32x4  = __attribute__((ext_vector_type(4))) float;

__device__ inline short f2bf(float f) {
    // round-to-nearest-even fp32 -> bf16
    unsigned int u = __float_as_uint(f);
    u += 0x7fffu + ((u >> 16) & 1u);
    return (short)(u >> 16);
}

__device__ inline bf16x8 cvt8(float4 a, float4 b) {
    bf16x8 r;
    r[0] = f2bf(a.x); r[1] = f2bf(a.y); r[2] = f2bf(a.z); r[3] = f2bf(a.w);
    r[4] = f2bf(b.x); r[5] = f2bf(b.y); r[6] = f2bf(b.z); r[7] = f2bf(b.w);
    return r;
}

__global__ __launch_bounds__(256, 8)
void split_linear_kernel(const float* __restrict__ x,
                         const float* __restrict__ W,
                         const float* __restrict__ bias,
                         float* __restrict__ out)
{
    const int d    = blockIdx.y;
    const int b0   = blockIdx.x * ROWS_PER_BLOCK;
    const int tid  = threadIdx.x;
    const int wave = tid >> 6;
    const int lane = tid & 63;
    const int lr   = lane & 15;   // A-row (g) / B-col (batch) / D-col (batch)
    const int lk   = lane >> 4;   // k-group / D row-quad

    // ---- A-operand: W fragments. A[i][k] = W[d][g = mt*16+lr][k = ks*32+lk*8+j] ----
    bf16x8 wf[2][4];
#pragma unroll
    for (int mt = 0; mt < 4; ++mt) {
        const float* wrow = W + ((size_t)d * FEAT + mt * 16 + lr) * FEAT + lk * 8;
#pragma unroll
        for (int ks = 0; ks < 2; ++ks) {
            float4 w0 = *(const float4*)(wrow + ks * 32);
            float4 w1 = *(const float4*)(wrow + ks * 32 + 4);
            wf[ks][mt] = cvt8(w0, w1);
        }
    }

    // ---- bias as accumulator init: D row g = mt*16 + lk*4 + r ----
    f32x4 bias4[4];
#pragma unroll
    for (int mt = 0; mt < 4; ++mt)
        bias4[mt] = *(const f32x4*)(bias + (size_t)d * FEAT + mt * 16 + lk * 4);

    // ---- software-pipelined main loop over 16-row batch tiles ----
    // B-operand: B[k][j] = x[b0 + tt*16 + j][d][k], lane j = lr, k = ks*32+lk*8+jj
    float4 rawA[4], rawB[4];
    {
        const float* xp = x + ((size_t)(b0 + wave * 16 + lr) * DIM + d) * FEAT + lk * 8;
        rawA[0] = *(const float4*)(xp);
        rawA[1] = *(const float4*)(xp + 4);
        rawA[2] = *(const float4*)(xp + 32);
        rawA[3] = *(const float4*)(xp + 36);
    }

#pragma unroll
    for (int t = 0; t < TILES_PER_WAVE; ++t) {
        float4* cur = (t & 1) ? rawB : rawA;
        float4* nxt = (t & 1) ? rawA : rawB;
        if (t + 1 < TILES_PER_WAVE) {
            const float* xp = x + ((size_t)(b0 + ((t + 1) * 4 + wave) * 16 + lr) * DIM + d) * FEAT + lk * 8;
            nxt[0] = *(const float4*)(xp);
            nxt[1] = *(const float4*)(xp + 4);
            nxt[2] = *(const float4*)(xp + 32);
            nxt[3] = *(const float4*)(xp + 36);
        }

        bf16x8 af0 = cvt8(cur[0], cur[1]);   // ks = 0
        bf16x8 af1 = cvt8(cur[2], cur[3]);   // ks = 1

        f32x4 acc[4];
#pragma unroll
        for (int mt = 0; mt < 4; ++mt) acc[mt] = bias4[mt];
#pragma unroll
        for (int mt = 0; mt < 4; ++mt)
            acc[mt] = __builtin_amdgcn_mfma_f32_16x16x32_bf16(wf[0][mt], af0, acc[mt], 0, 0, 0);
#pragma unroll
        for (int mt = 0; mt < 4; ++mt)
            acc[mt] = __builtin_amdgcn_mfma_f32_16x16x32_bf16(wf[1][mt], af1, acc[mt], 0, 0, 0);

        // ---- store: lane owns out[b0+tt*16+lr][d][mt*16 + lk*4 .. +3] (float4, via L2) ----
        float* op = out + ((size_t)(b0 + (t * 4 + wave) * 16 + lr) * DIM + d) * FEAT + lk * 4;
#pragma unroll
        for (int mt = 0; mt < 4; ++mt)
            *(f32x4*)(op + mt * 16) = acc[mt];
    }
}

extern "C" void kernel_launch(void* const* d_in, const int* in_sizes, int n_in,
                              void* d_out, int out_size, void* d_ws, size_t ws_size,
                              hipStream_t stream) {
    const float* x    = (const float*)d_in[0];
    const float* W    = (const float*)d_in[1];
    const float* bias = (const float*)d_in[2];
    float* out        = (float*)d_out;

    dim3 grid(BATCH / ROWS_PER_BLOCK, DIM, 1);  // (4, 512)
    dim3 block(256, 1, 1);
    split_linear_kernel<<<grid, block, 0, stream>>>(x, W, bias, out);
}

// Round 4
// 136.457 us; speedup vs baseline: 1.9027x; 1.9027x over previous
//
#include <hip/hip_runtime.h>
#include <hip/hip_bf16.h>

#define DIM  512
#define FEAT 64
#define BATCH 2048

#define ROWS_PER_BLOCK 512
#define TILES_PER_WAVE 8   // ROWS_PER_BLOCK / (4 waves * 16 rows)

using bf16x8 = __attribute__((ext_vector_type(8))) short;
using f32x4  = __attribute__((ext_vector_type(4))) float;

__device__ inline short f2bf(float f) {
    unsigned int u = __float_as_uint(f);
    u += 0x7fffu + ((u >> 16) & 1u);
    return (short)(u >> 16);
}

__device__ inline bf16x8 cvt8(float4 a, float4 b) {
    bf16x8 r;
    r[0] = f2bf(a.x); r[1] = f2bf(a.y); r[2] = f2bf(a.z); r[3] = f2bf(a.w);
    r[4] = f2bf(b.x); r[5] = f2bf(b.y); r[6] = f2bf(b.z); r[7] = f2bf(b.w);
    return r;
}

__global__ __launch_bounds__(256, 4)
void split_linear_kernel(const float* __restrict__ x,
                         const float* __restrict__ W,
                         const float* __restrict__ bias,
                         float* __restrict__ out)
{
    // ---- chunked XCD swizzle: each XCD owns a contiguous 256-wide d-range ----
    // nid: d fastest, so co-resident blocks on one XCD stream CONTIGUOUS memory.
    const int id    = blockIdx.x;          // 0..2047
    const int xcd   = id & 7;
    const int chunk = id >> 3;             // 0..255
    const int nid   = xcd * 256 + chunk;
    const int d     = nid & (DIM - 1);
    const int b0    = (nid >> 9) * ROWS_PER_BLOCK;

    const int tid  = threadIdx.x;
    const int wave = tid >> 6;
    const int lane = tid & 63;
    const int lr   = lane & 15;   // A-row (g) / B-col (batch) / D-col (batch)
    const int lk   = lane >> 4;   // k-group / D row-quad

    // ---- bias in LDS (saves 16 VGPR vs register copy) ----
    __shared__ float blds[FEAT];
    if (tid < FEAT) blds[tid] = bias[(size_t)d * FEAT + tid];

    // ---- A-operand: W fragments. A[i][k] = W[d][g = mt*16+lr][k = ks*32+lk*8+j] ----
    bf16x8 wf[2][4];
#pragma unroll
    for (int mt = 0; mt < 4; ++mt) {
        const float* wrow = W + ((size_t)d * FEAT + mt * 16 + lr) * FEAT + lk * 8;
#pragma unroll
        for (int ks = 0; ks < 2; ++ks) {
            float4 w0 = *(const float4*)(wrow + ks * 32);
            float4 w1 = *(const float4*)(wrow + ks * 32 + 4);
            wf[ks][mt] = cvt8(w0, w1);
        }
    }
    __syncthreads();

    // ---- main loop; single raw buffer, prefetch reuses the same registers ----
    float4 raw[4];
    {
        const float* xp = x + ((size_t)(b0 + wave * 16 + lr) * DIM + d) * FEAT + lk * 8;
        raw[0] = *(const float4*)(xp);
        raw[1] = *(const float4*)(xp + 4);
        raw[2] = *(const float4*)(xp + 32);
        raw[3] = *(const float4*)(xp + 36);
    }

    for (int t = 0; t < TILES_PER_WAVE; ++t) {
        // consume raws into bf16 fragments (raw regs die here)
        bf16x8 af0 = cvt8(raw[0], raw[1]);   // ks = 0
        bf16x8 af1 = cvt8(raw[2], raw[3]);   // ks = 1

        // issue next tile's loads NOW — they overlap the MFMAs + stores below
        if (t + 1 < TILES_PER_WAVE) {
            const float* xp = x + ((size_t)(b0 + ((t + 1) * 4 + wave) * 16 + lr) * DIM + d) * FEAT + lk * 8;
            raw[0] = *(const float4*)(xp);
            raw[1] = *(const float4*)(xp + 4);
            raw[2] = *(const float4*)(xp + 32);
            raw[3] = *(const float4*)(xp + 36);
        }

        // acc init = bias (broadcast reads from LDS)
        f32x4 acc[4];
#pragma unroll
        for (int mt = 0; mt < 4; ++mt)
            acc[mt] = *(const f32x4*)&blds[mt * 16 + lk * 4];

#pragma unroll
        for (int mt = 0; mt < 4; ++mt)
            acc[mt] = __builtin_amdgcn_mfma_f32_16x16x32_bf16(wf[0][mt], af0, acc[mt], 0, 0, 0);
#pragma unroll
        for (int mt = 0; mt < 4; ++mt)
            acc[mt] = __builtin_amdgcn_mfma_f32_16x16x32_bf16(wf[1][mt], af1, acc[mt], 0, 0, 0);

        // store: lane owns out[b0+tt*16+lr][d][mt*16 + lk*4 .. +3] (float4, via L2)
        float* op = out + ((size_t)(b0 + (t * 4 + wave) * 16 + lr) * DIM + d) * FEAT + lk * 4;
#pragma unroll
        for (int mt = 0; mt < 4; ++mt)
            *(f32x4*)(op + mt * 16) = acc[mt];
    }
}

extern "C" void kernel_launch(void* const* d_in, const int* in_sizes, int n_in,
                              void* d_out, int out_size, void* d_ws, size_t ws_size,
                              hipStream_t stream) {
    const float* x    = (const float*)d_in[0];
    const float* W    = (const float*)d_in[1];
    const float* bias = (const float*)d_in[2];
    float* out        = (float*)d_out;

    dim3 grid(DIM * (BATCH / ROWS_PER_BLOCK), 1, 1);  // 2048 blocks, 1-D
    dim3 block(256, 1, 1);
    split_linear_kernel<<<grid, block, 0, stream>>>(x, W, bias, out);
}

// Round 5
// 133.774 us; speedup vs baseline: 1.9409x; 1.0201x over previous
//
#include <hip/hip_runtime.h>
#include <hip/hip_bf16.h>

#define DIM  512
#define FEAT 64
#define BATCH 2048

#define ROWS_PER_BLOCK 512
#define TILES_PER_WAVE 8   // ROWS_PER_BLOCK / (4 waves * 16 rows)
#define SLOTS 3            // per-wave LDS circular-buffer depth

using bf16x8 = __attribute__((ext_vector_type(8))) short;
using f32x4  = __attribute__((ext_vector_type(4))) float;

typedef __attribute__((address_space(3))) float lds_f;
typedef __attribute__((address_space(1))) const float glb_f;

__device__ inline short f2bf(float f) {
    unsigned int u = __float_as_uint(f);
    u += 0x7fffu + ((u >> 16) & 1u);
    return (short)(u >> 16);
}

__device__ inline bf16x8 cvt8(float4 a, float4 b) {
    bf16x8 r;
    r[0] = f2bf(a.x); r[1] = f2bf(a.y); r[2] = f2bf(a.z); r[3] = f2bf(a.w);
    r[4] = f2bf(b.x); r[5] = f2bf(b.y); r[6] = f2bf(b.z); r[7] = f2bf(b.w);
    return r;
}

__global__ __launch_bounds__(256, 3)
void split_linear_kernel(const float* __restrict__ x,
                         const float* __restrict__ W,
                         const float* __restrict__ bias,
                         float* __restrict__ out)
{
    // per-wave staging buffers: [wave][slot][16 rows][64 f32], row-major,
    // 16B-chunk XOR-swizzled by (row&7) on BOTH write-source and read side.
    __shared__ float xlds[4][SLOTS][1024];
    __shared__ float blds[FEAT];

    // chunked XCD swizzle, d fastest (from R4)
    const int id    = blockIdx.x;
    const int xcd   = id & 7;
    const int chunk = id >> 3;
    const int nid   = xcd * 256 + chunk;
    const int d     = nid & (DIM - 1);
    const int b0    = (nid >> 9) * ROWS_PER_BLOCK;

    const int tid  = threadIdx.x;
    const int wave = tid >> 6;
    const int lane = tid & 63;
    const int lr   = lane & 15;   // A-row (g) / B-col (batch row)
    const int lk   = lane >> 4;   // k-group / D row-quad

    if (tid < FEAT) blds[tid] = bias[(size_t)d * FEAT + tid];
    __syncthreads();   // only bias outstanding here — cheap drain

    // ---- A-operand: W fragments (registers, reused over all tiles) ----
    bf16x8 wf[2][4];
#pragma unroll
    for (int mt = 0; mt < 4; ++mt) {
        const float* wrow = W + ((size_t)d * FEAT + mt * 16 + lr) * FEAT + lk * 8;
#pragma unroll
        for (int ks = 0; ks < 2; ++ks) {
            float4 w0 = *(const float4*)(wrow + ks * 32);
            float4 w1 = *(const float4*)(wrow + ks * 32 + 4);
            wf[ks][mt] = cvt8(w0, w1);
        }
    }

    // ---- async stage: tile tt -> xlds[wave][slot] ----
    // instr i: 4 rows (i*4 + lane>>4), each 256B fully covered by 16 lanes.
    // source chunk pre-swizzled so LDS ends up row-major with c^=(r&7).
    auto stage = [&](int slot, int tt) {
#pragma unroll
        for (int i = 0; i < 4; ++i) {
            const int r = i * 4 + (lane >> 4);          // row within tile
            const int c = (lane & 15) ^ (r & 7);        // logical 16B chunk
            const float* gp = x + ((size_t)(b0 + tt * 16 + r) * DIM + d) * FEAT + c * 4;
            __builtin_amdgcn_global_load_lds((glb_f*)gp,
                                             (lds_f*)&xlds[wave][slot][i * 256],
                                             16, 0, 0);
        }
    };

    // prologue: 2 tiles in flight (8 vmem ops)
    stage(0, wave);
    stage(1, 4 + wave);

#pragma unroll
    for (int t = 0; t < TILES_PER_WAVE; ++t) {
        // counted wait: retire exactly this tile's 4 staging ops (oldest),
        // keep the rest (next stage + stores) in flight. Never vmcnt(0).
        if (t == 0 || t == TILES_PER_WAVE - 1)
            asm volatile("s_waitcnt vmcnt(4)" ::: "memory");
        else
            asm volatile("s_waitcnt vmcnt(8)" ::: "memory");
        __builtin_amdgcn_sched_barrier(0);   // fence: no ds_read/stage hoists past

        const float* sl = &xlds[wave][t % SLOTS][0];
        // fragment reads: row lr, 8 f32 per ks, via 2 swizzled ds_read_b128
        float4 p0a = *(const float4*)&sl[lr * 64 + (((lk * 2 + 0) ^ (lr & 7)) << 2)];
        float4 p0b = *(const float4*)&sl[lr * 64 + (((lk * 2 + 1) ^ (lr & 7)) << 2)];
        float4 p1a = *(const float4*)&sl[lr * 64 + (((8 + lk * 2 + 0) ^ (lr & 7)) << 2)];
        float4 p1b = *(const float4*)&sl[lr * 64 + (((8 + lk * 2 + 1) ^ (lr & 7)) << 2)];

        bf16x8 af0 = cvt8(p0a, p0b);   // ks = 0
        bf16x8 af1 = cvt8(p1a, p1b);   // ks = 1

        // issue stage for tile t+2 (slot was consumed in iter t-1; safe)
        if (t + 2 < TILES_PER_WAVE)
            stage((t + 2) % SLOTS, (t + 2) * 4 + wave);

        // acc init = bias
        f32x4 acc[4];
#pragma unroll
        for (int mt = 0; mt < 4; ++mt)
            acc[mt] = *(const f32x4*)&blds[mt * 16 + lk * 4];

#pragma unroll
        for (int mt = 0; mt < 4; ++mt)
            acc[mt] = __builtin_amdgcn_mfma_f32_16x16x32_bf16(wf[0][mt], af0, acc[mt], 0, 0, 0);
#pragma unroll
        for (int mt = 0; mt < 4; ++mt)
            acc[mt] = __builtin_amdgcn_mfma_f32_16x16x32_bf16(wf[1][mt], af1, acc[mt], 0, 0, 0);

        // store: lane owns out[b0+tt*16+lr][d][mt*16 + lk*4 .. +3]
        float* op = out + ((size_t)(b0 + (t * 4 + wave) * 16 + lr) * DIM + d) * FEAT + lk * 4;
#pragma unroll
        for (int mt = 0; mt < 4; ++mt)
            *(f32x4*)(op + mt * 16) = acc[mt];
    }
}

extern "C" void kernel_launch(void* const* d_in, const int* in_sizes, int n_in,
                              void* d_out, int out_size, void* d_ws, size_t ws_size,
                              hipStream_t stream) {
    const float* x    = (const float*)d_in[0];
    const float* W    = (const float*)d_in[1];
    const float* bias = (const float*)d_in[2];
    float* out        = (float*)d_out;

    dim3 grid(DIM * (BATCH / ROWS_PER_BLOCK), 1, 1);  // 2048 blocks
    dim3 block(256, 1, 1);
    split_linear_kernel<<<grid, block, 0, stream>>>(x, W, bias, out);
}